// Round 6
// baseline (846.324 us; speedup 1.0000x reference)
//
#include <hip/hip_runtime.h>
#include <math.h>

// Problem constants
#define BS_ 4
#define N_  2048
#define D_  1024
#define H_  8
#define DH_ 128

typedef __attribute__((ext_vector_type(8))) short short8;
typedef __attribute__((ext_vector_type(4))) short short4_t;
typedef __attribute__((ext_vector_type(4))) float float4_t;
typedef unsigned short u16;

__device__ __forceinline__ u16 f2bf(float f) {
    union { float f; unsigned u; } v; v.f = f;
    unsigned r = v.u + 0x7FFFu + ((v.u >> 16) & 1u);   // RNE
    return (u16)(r >> 16);
}
__device__ __forceinline__ float bf2f(u16 h) {
    union { unsigned u; float f; } v; v.u = ((unsigned)h) << 16;
    return v.f;
}
__device__ __forceinline__ void split4(float a, float b, float c, float d,
                                       short4_t* hi, short4_t* lo) {
    u16 h0 = f2bf(a), h1 = f2bf(b), h2 = f2bf(c), h3 = f2bf(d);
    (*hi)[0] = (short)h0; (*hi)[1] = (short)h1; (*hi)[2] = (short)h2; (*hi)[3] = (short)h3;
    (*lo)[0] = (short)f2bf(a - bf2f(h0));
    (*lo)[1] = (short)f2bf(b - bf2f(h1));
    (*lo)[2] = (short)f2bf(c - bf2f(h2));
    (*lo)[3] = (short)f2bf(d - bf2f(h3));
}

// async global->LDS, 16B per lane; LDS dest = wave-uniform base + lane*16.
__device__ __forceinline__ void gl_lds16(const void* g, void* l) {
    __builtin_amdgcn_global_load_lds(
        (const __attribute__((address_space(1))) unsigned int*)g,
        (__attribute__((address_space(3))) unsigned int*)l,
        16, 0, 0);
}

// ---------------------------------------------------------------------------
// Kernel 1: AP table, bf16.
// ---------------------------------------------------------------------------
__global__ void ap_kernel(unsigned int* __restrict__ APb) {
    int idx = blockIdx.x * blockDim.x + threadIdx.x;   // 2,097,152 = 2048*1024
    int p = idx >> 10, u = idx & 1023;
    float ex = exp2f(-(float)u * (13.287712379549449f / 512.0f));
    float angle = (float)p * ex;
    unsigned pack = (unsigned)f2bf(sinf(angle)) | ((unsigned)f2bf(cosf(angle)) << 16);
    APb[(size_t)p * (N_ / 2) + u] = pack;   // shorts at p*2048 + 2u
}

// ---------------------------------------------------------------------------
// Kernel 2: fp32 -> bf16 hi/lo pre-split of X, Wq|Wk (cat), Wv (hi), Wout (hi).
// ---------------------------------------------------------------------------
__global__ void split_kernel(const float* __restrict__ x,
                             const float* __restrict__ Wq, const float* __restrict__ Wk,
                             const float* __restrict__ Wv, const float* __restrict__ Wo,
                             u16* __restrict__ Xhi, u16* __restrict__ Xlo,
                             u16* __restrict__ Whi, u16* __restrict__ Wlo,
                             u16* __restrict__ Wvhi, u16* __restrict__ Wohi) {
    int i = blockIdx.x * 256 + threadIdx.x;            // 3,145,728 float4s
    const float* src; u16 *dhi, *dlo; size_t off;
    if (i < 2097152)      { src = x  + 4*(size_t)i;             dhi = Xhi;  dlo = Xlo;  off = 4*(size_t)i; }
    else if (i < 2359296) { size_t j = i - 2097152; src = Wq + 4*j; dhi = Whi; dlo = Wlo; off = 4*j; }
    else if (i < 2621440) { size_t j = i - 2359296; src = Wk + 4*j; dhi = Whi; dlo = Wlo; off = 1048576 + 4*j; }
    else if (i < 2883584) { size_t j = i - 2621440; src = Wv + 4*j; dhi = Wvhi; dlo = nullptr; off = 4*j; }
    else                  { size_t j = i - 2883584; src = Wo + 4*j; dhi = Wohi; dlo = nullptr; off = 4*j; }
    float4 v = *(const float4*)src;
    short4_t hi, lo;
    split4(v.x, v.y, v.z, v.w, &hi, &lo);
    *(short4_t*)(dhi + off) = hi;
    if (dlo) *(short4_t*)(dlo + off) = lo;
}

// ---------------------------------------------------------------------------
// Kernel 3: Q,K projections.  3-term bf16 split, m97 structure (unchanged).
// ---------------------------------------------------------------------------
__global__ __launch_bounds__(256, 4) void qk_gemm(
    const u16* __restrict__ Xhi, const u16* __restrict__ Xlo,
    const u16* __restrict__ Whi, const u16* __restrict__ Wlo,
    u16* __restrict__ Qhi, u16* __restrict__ Qlo,
    u16* __restrict__ Khi, u16* __restrict__ Klo)
{
    const int mt = blockIdx.x;   // 64
    const int nt = blockIdx.y;   // 16
    const int tid = threadIdx.x, wave = tid >> 6, lane = tid & 63;
    const int quad = lane >> 4, l16 = lane & 15;

    __shared__ __align__(16) u16 sA[2][128 * 32];
    __shared__ __align__(16) u16 sB[2][128 * 32];

    const int srow = lane >> 2;
    const int scol = (lane & 3) * 8;
    const size_t aoff = ((size_t)(mt * 128) + srow) * 1024 + scol;
    const size_t boff = ((size_t)(nt * 128) + srow) * 1024 + scol;
    const int r0 = wave * 16, r1 = 64 + wave * 16;

    float4_t acc[2][8];
#pragma unroll
    for (int i = 0; i < 2; ++i)
#pragma unroll
        for (int j = 0; j < 8; ++j) acc[i][j] = (float4_t)(0.f);

    for (int kt = 0; kt < 32; ++kt) {
        __syncthreads();
        const int kc0 = kt * 32;
        gl_lds16(Xhi + aoff + (size_t)r0 * 1024 + kc0, &sA[0][r0 * 32]);
        gl_lds16(Xhi + aoff + (size_t)r1 * 1024 + kc0, &sA[0][r1 * 32]);
        gl_lds16(Xlo + aoff + (size_t)r0 * 1024 + kc0, &sA[1][r0 * 32]);
        gl_lds16(Xlo + aoff + (size_t)r1 * 1024 + kc0, &sA[1][r1 * 32]);
        gl_lds16(Whi + boff + (size_t)r0 * 1024 + kc0, &sB[0][r0 * 32]);
        gl_lds16(Whi + boff + (size_t)r1 * 1024 + kc0, &sB[0][r1 * 32]);
        gl_lds16(Wlo + boff + (size_t)r0 * 1024 + kc0, &sB[1][r0 * 32]);
        gl_lds16(Wlo + boff + (size_t)r1 * 1024 + kc0, &sB[1][r1 * 32]);
        __syncthreads();

#pragma unroll
        for (int t = 0; t < 3; ++t) {
            const u16* As = sA[t == 2 ? 1 : 0];
            const u16* Bs = sB[t == 1 ? 1 : 0];
            short8 afr[2];
#pragma unroll
            for (int mi = 0; mi < 2; ++mi)
                afr[mi] = *(const short8*)(As + (wave * 32 + mi * 16 + l16) * 32 + quad * 8);
#pragma unroll
            for (int ne = 0; ne < 8; ++ne) {
                short8 bfr = *(const short8*)(Bs + (ne * 16 + l16) * 32 + quad * 8);
#pragma unroll
                for (int mi = 0; mi < 2; ++mi)
                    acc[mi][ne] = __builtin_amdgcn_mfma_f32_16x16x32_bf16(afr[mi], bfr, acc[mi][ne], 0, 0, 0);
            }
        }
    }

    const int b = mt >> 4, q0 = (mt & 15) * 128;
    const bool isQ = (nt < 8);
    u16* Hi = isQ ? Qhi : Khi;
    u16* Lo = isQ ? Qlo : Klo;
    const int h = isQ ? nt : nt - 8;
    const size_t base = (size_t)(b * 8 + h) * N_ * DH_;
#pragma unroll
    for (int mi = 0; mi < 2; ++mi)
#pragma unroll
        for (int ne = 0; ne < 8; ++ne)
#pragma unroll
            for (int r = 0; r < 4; ++r) {
                int q = q0 + wave * 32 + mi * 16 + quad * 4 + r;
                int e = ne * 16 + l16;
                float v = acc[mi][ne][r];
                u16 hv = f2bf(v);
                Hi[base + (size_t)q * DH_ + e] = hv;
                Lo[base + (size_t)q * DH_ + e] = f2bf(v - bf2f(hv));
            }
}

// ---------------------------------------------------------------------------
// Kernel 4: V^T[bh][e][q]  (1-term bf16, unchanged).
// ---------------------------------------------------------------------------
__global__ __launch_bounds__(256, 4) void v_gemm(
    const u16* __restrict__ Wvhi, const u16* __restrict__ Xhi,
    u16* __restrict__ VT)
{
    const int qt = blockIdx.x;   // 16
    const int bh = blockIdx.y;   // 32
    const int b = bh >> 3, h = bh & 7;
    const int tid = threadIdx.x, wave = tid >> 6, lane = tid & 63;
    const int quad = lane >> 4, l16 = lane & 15;

    __shared__ __align__(16) u16 sA[128 * 32];
    __shared__ __align__(16) u16 sB[128 * 32];

    const int srow = lane >> 2, scol = (lane & 3) * 8;
    const size_t aoff = ((size_t)(h * 128) + srow) * 1024 + scol;
    const size_t boff = ((size_t)(b * N_ + qt * 128) + srow) * 1024 + scol;
    const int r0 = wave * 16, r1 = 64 + wave * 16;

    float4_t acc[2][8];
#pragma unroll
    for (int i = 0; i < 2; ++i)
#pragma unroll
        for (int j = 0; j < 8; ++j) acc[i][j] = (float4_t)(0.f);

    for (int kt = 0; kt < 32; ++kt) {
        __syncthreads();
        const int kc0 = kt * 32;
        gl_lds16(Wvhi + aoff + (size_t)r0 * 1024 + kc0, &sA[r0 * 32]);
        gl_lds16(Wvhi + aoff + (size_t)r1 * 1024 + kc0, &sA[r1 * 32]);
        gl_lds16(Xhi  + boff + (size_t)r0 * 1024 + kc0, &sB[r0 * 32]);
        gl_lds16(Xhi  + boff + (size_t)r1 * 1024 + kc0, &sB[r1 * 32]);
        __syncthreads();

        short8 afr[2];
#pragma unroll
        for (int mi = 0; mi < 2; ++mi)
            afr[mi] = *(const short8*)(sA + (wave * 32 + mi * 16 + l16) * 32 + quad * 8);
#pragma unroll
        for (int ne = 0; ne < 8; ++ne) {
            short8 bfr = *(const short8*)(sB + (ne * 16 + l16) * 32 + quad * 8);
#pragma unroll
            for (int mi = 0; mi < 2; ++mi)
                acc[mi][ne] = __builtin_amdgcn_mfma_f32_16x16x32_bf16(afr[mi], bfr, acc[mi][ne], 0, 0, 0);
        }
    }

    u16* Cg = VT + (size_t)bh * DH_ * N_;
#pragma unroll
    for (int mi = 0; mi < 2; ++mi)
#pragma unroll
        for (int ne = 0; ne < 8; ++ne)
#pragma unroll
            for (int r = 0; r < 4; ++r) {
                int e = wave * 32 + mi * 16 + quad * 4 + r;
                int q = qt * 128 + ne * 16 + l16;
                Cg[(size_t)e * N_ + q] = f2bf(acc[mi][ne][r]);
            }
}

// ---------------------------------------------------------------------------
// Kernel 5 (pass A): l_j = sum_k exp(E[j,k]).  UNCHANGED (chain must remain
// bitwise-identical per 16x16 tile: t-major, kc-minor, 12 steps).
// ---------------------------------------------------------------------------
__global__ __launch_bounds__(512, 2) void rowstats_kernel(
    const u16* __restrict__ Qhi, const u16* __restrict__ Qlo,
    const u16* __restrict__ Khi, const u16* __restrict__ Klo,
    const u16* __restrict__ APb,
    const int* __restrict__ mask,
    float* __restrict__ lrow)
{
    const int jt = blockIdx.x;    // 32 j-tiles of 64
    const int bh = blockIdx.y;    // 32
    const int b = bh >> 3;
    const int tid = threadIdx.x, wave = tid >> 6, lane = tid & 63;
    const int quad = lane >> 4, l16 = lane & 15;
    const int jsub = (wave & 3) * 16, khalf = wave >> 2;

    __shared__ __align__(16) u16 ldsQ[64 * 264];       // resident, split
    __shared__ __align__(16) u16 ldsK[2][64 * 264];    // streamed, split
    __shared__ __align__(16) u16 ldsAP[2][64 * 72];    // streamed
    __shared__ int   s_mk[2][64];
    __shared__ float psum[64 * 2];

    const size_t Qbase = ((size_t)bh * N_ + (size_t)jt * 64) * DH_;
    for (int c = tid; c < 2048; c += 512) {
        int row = c >> 5, half = (c >> 4) & 1, seg = c & 15;
        *(short8*)(ldsQ + row * 264 + half * 128 + seg * 8) =
            *(const short8*)((half ? Qlo : Qhi) + Qbase + (size_t)row * DH_ + seg * 8);
    }
    {
        const size_t Kb = ((size_t)bh * N_) * DH_;
        for (int c = tid; c < 2048; c += 512) {
            int row = c >> 5, half = (c >> 4) & 1, seg = c & 15;
            *(short8*)(ldsK[0] + row * 264 + half * 128 + seg * 8) =
                *(const short8*)((half ? Klo : Khi) + Kb + (size_t)row * DH_ + seg * 8);
        }
        int row = tid >> 3, seg = tid & 7;
        *(short8*)(ldsAP[0] + row * 72 + seg * 8) =
            *(const short8*)(APb + (size_t)(jt * 64 + row) * N_ + seg * 8);
        if (tid < 64) s_mk[0][tid] = mask[b * N_ + tid];
    }

    float p[4] = {0.f, 0.f, 0.f, 0.f};
    int mj_on[4];
#pragma unroll
    for (int r = 0; r < 4; ++r)
        mj_on[r] = mask[b * N_ + jt * 64 + jsub + quad * 4 + r];

    __syncthreads();

    for (int kt = 0; kt < 32; ++kt) {
        const int cur = kt & 1, nxt = cur ^ 1;
        short8 rK[4], rAP;
        int rmk = 0;
        if (kt < 31) {
            const size_t Kb2 = ((size_t)bh * N_ + (size_t)(kt + 1) * 64) * DH_;
#pragma unroll
            for (int i = 0; i < 4; ++i) {
                int c = tid + i * 512;
                int row = c >> 5, half = (c >> 4) & 1, seg = c & 15;
                rK[i] = *(const short8*)((half ? Klo : Khi) + Kb2 + (size_t)row * DH_ + seg * 8);
            }
            int row = tid >> 3, seg = tid & 7;
            rAP = *(const short8*)(APb + (size_t)(jt * 64 + row) * N_ + (kt + 1) * 64 + seg * 8);
            if (tid < 64) rmk = mask[b * N_ + (kt + 1) * 64 + tid];
        }

        float4_t acc[2];
        acc[0] = (float4_t)(0.f); acc[1] = (float4_t)(0.f);
#pragma unroll
        for (int t = 0; t < 3; ++t) {
            const int ab = (t == 2) ? 128 : 0;
            const int bb = (t == 1) ? 128 : 0;
#pragma unroll
            for (int kc = 0; kc < 4; ++kc) {
                short8 afr = *(const short8*)(ldsQ + (jsub + l16) * 264 + ab + kc * 32 + quad * 8);
#pragma unroll
                for (int nk = 0; nk < 2; ++nk) {
                    short8 bfr = *(const short8*)(ldsK[cur] + (khalf * 32 + nk * 16 + l16) * 264 + bb + kc * 32 + quad * 8);
                    acc[nk] = __builtin_amdgcn_mfma_f32_16x16x32_bf16(afr, bfr, acc[nk], 0, 0, 0);
                }
            }
        }

#pragma unroll
        for (int r = 0; r < 4; ++r) {
            int jl = jsub + quad * 4 + r;
            int on = mj_on[r];
            float s = 0.f;
#pragma unroll
            for (int nk = 0; nk < 2; ++nk) {
                int kk = khalf * 32 + nk * 16 + l16;
                float e = acc[nk][r] + bf2f(ldsAP[cur][jl * 72 + kk]);
                e = (on && s_mk[cur][kk]) ? e : -1.0e9f;
                s += __expf(e);
            }
            p[r] += s;
        }

        if (kt < 31) {
#pragma unroll
            for (int i = 0; i < 4; ++i) {
                int c = tid + i * 512;
                int row = c >> 5, half = (c >> 4) & 1, seg = c & 15;
                *(short8*)(ldsK[nxt] + row * 264 + half * 128 + seg * 8) = rK[i];
            }
            int row = tid >> 3, seg = tid & 7;
            *(short8*)(ldsAP[nxt] + row * 72 + seg * 8) = rAP;
            if (tid < 64) s_mk[nxt][tid] = rmk;
        }
        __syncthreads();
    }

#pragma unroll
    for (int r = 0; r < 4; ++r) {
        float s = p[r];
        for (int off = 1; off < 16; off <<= 1)
            s += __shfl_xor(s, off, 64);
        if (l16 == 0)
            psum[(jsub + quad * 4 + r) * 2 + khalf] = s;
    }
    __syncthreads();
    if (tid < 64)
        lrow[(size_t)bh * N_ + jt * 64 + tid] = psum[tid * 2] + psum[tid * 2 + 1];
}

// ---------------------------------------------------------------------------
// Kernel 6 (pass B): y[i,e] = sum_j A[j,i] V[j,e], A = exp(E)/l_j.
// LDS-traffic-optimized: j-tile 64 (Q dbuf in LDS), K_i 128 resident,
// V fragments straight from global into VGPRs (no ldsV), AP via prefetched
// global scalars (no ldsAP).  MFMA1 wave grid 2j x 4i (32x32 per wave, 1.0
// LDS-read/MFMA); MFMA2 wave grid 4i x 2e.  ldsA stride 64 + XOR swizzle.
// Per-element E chain = 12 MFMAs t-major/kc-minor, bitwise == rowstats.
// ---------------------------------------------------------------------------
__global__ __launch_bounds__(512, 2) void attn_kernel(
    const u16* __restrict__ Qhi, const u16* __restrict__ Qlo,
    const u16* __restrict__ Khi, const u16* __restrict__ Klo,
    const u16* __restrict__ VT,
    const u16* __restrict__ APb,
    const int* __restrict__ mask,
    const float* __restrict__ lrow,
    u16* __restrict__ yout,               // [BS,N,D] bf16 (ws)
    float* __restrict__ aout)             // [BS,N,N] fp32 (d_out tail)
{
    const int it = blockIdx.x;   // 16 i-tiles (keys)
    const int bh = blockIdx.y;   // 32
    const int b = bh >> 3, h = bh & 7;
    const int tid = threadIdx.x, wave = tid >> 6, lane = tid & 63;  // 8 waves
    const int quad = lane >> 4, l16 = lane & 15;
    const int jw = wave >> 2, iw = wave & 3;       // MFMA1: 2j x 4i
    const int e0 = (wave >> 2) * 64, i0y = (wave & 3) * 32;  // MFMA2: 4i x 2e

    __shared__ __align__(16) u16 ldsK[128 * 264];     // K_i split, resident (66 KB)
    __shared__ __align__(16) u16 ldsQ[2][64 * 264];   // Q_j split, dbuf (66 KB)
    __shared__ __align__(16) u16 ldsA[128 * 64];      // A^T swizzled (16 KB)
    __shared__ float s_il[2][64];
    __shared__ int   s_dead[2][64];
    __shared__ int   s_mj[2][64];

    // resident K (8 b128 stores per thread)
    const size_t Kbase = ((size_t)bh * N_ + (size_t)it * 128) * DH_;
    for (int c = tid; c < 4096; c += 512) {
        int row = c >> 5, grp = c & 31, half = grp >> 4, seg = grp & 15;
        *(short8*)(ldsK + row * 264 + half * 128 + seg * 8) =
            *(const short8*)((half ? Klo : Khi) + Kbase + (size_t)row * DH_ + seg * 8);
    }
    // Q buf0 + stats buf0
    {
        const size_t Qb0 = (size_t)bh * N_ * DH_;
        for (int c = tid; c < 2048; c += 512) {
            int row = c >> 5, grp = c & 31, half = grp >> 4, seg = grp & 15;
            *(short8*)(ldsQ[0] + row * 264 + half * 128 + seg * 8) =
                *(const short8*)((half ? Qlo : Qhi) + Qb0 + (size_t)row * DH_ + seg * 8);
        }
        if (tid < 64) {
            float l = lrow[(size_t)bh * N_ + tid];
            int mj = mask[b * N_ + tid];
            int alive = (mj != 0) && (l > 0.f);
            s_il[0][tid]   = alive ? 1.0f / l : 0.f;
            s_dead[0][tid] = !alive;
            s_mj[0][tid]   = mj;
        }
    }

    int ion[2];
#pragma unroll
    for (int ni = 0; ni < 2; ++ni)
        ion[ni] = mask[b * N_ + it * 128 + iw * 32 + ni * 16 + l16];

    float4_t accy[2][4];   // [m2][ne]
#pragma unroll
    for (int m2 = 0; m2 < 2; ++m2)
#pragma unroll
        for (int ne = 0; ne < 4; ++ne) accy[m2][ne] = (float4_t)(0.f);

    const bool do_aout = (h == 7);
    const float inv_n = 1.0f / (float)N_;
    const u16* VTb = VT + (size_t)bh * DH_ * N_;

    __syncthreads();

    for (int jt = 0; jt < 32; ++jt) {
        const int cur = jt & 1, nxt = cur ^ 1;
        const int j0 = jt * 64;

        // --- prefetch NEXT Q-tile + stats into registers
        short8 rQ[4];
        float r_il = 0.f; int r_dead = 1, r_mj = 0;
        if (jt < 31) {
            const size_t Qb2 = ((size_t)bh * N_ + j0 + 64) * DH_;
#pragma unroll
            for (int i = 0; i < 4; ++i) {
                int c = tid + i * 512;
                int row = c >> 5, grp = c & 31, half = grp >> 4, seg = grp & 15;
                rQ[i] = *(const short8*)((half ? Qlo : Qhi) + Qb2 + (size_t)row * DH_ + seg * 8);
            }
            if (tid < 64) {
                float l = lrow[(size_t)bh * N_ + j0 + 64 + tid];
                r_mj = mask[b * N_ + j0 + 64 + tid];
                int alive = (r_mj != 0) && (l > 0.f);
                r_il = alive ? 1.0f / l : 0.f;
                r_dead = !alive;
            }
        }
        // --- CURRENT V fragments (global -> VGPR, consumed in MFMA2)
        short8 rV[2][4];
#pragma unroll
        for (int kcj = 0; kcj < 2; ++kcj)
#pragma unroll
            for (int ne = 0; ne < 4; ++ne)
                rV[kcj][ne] = *(const short8*)(VTb + (size_t)(e0 + ne * 16 + l16) * N_
                                               + j0 + kcj * 32 + quad * 8);
        // --- CURRENT AP scalars (global u16, consumed in epilogue)
        u16 apv[2][2][4];
#pragma unroll
        for (int mj = 0; mj < 2; ++mj)
#pragma unroll
            for (int ni = 0; ni < 2; ++ni)
#pragma unroll
                for (int r = 0; r < 4; ++r)
                    apv[mj][ni][r] = APb[(size_t)(j0 + jw * 32 + mj * 16 + quad * 4 + r) * N_
                                         + it * 128 + iw * 32 + ni * 16 + l16];

        // --- MFMA1: S[32j x 32i per wave], chain t-major kc-minor (== rowstats)
        float4_t accs[2][2];
#pragma unroll
        for (int mj = 0; mj < 2; ++mj)
#pragma unroll
            for (int ni = 0; ni < 2; ++ni) accs[mj][ni] = (float4_t)(0.f);
#pragma unroll
        for (int t = 0; t < 3; ++t) {
            const int ab = (t == 2) ? 128 : 0;
            const int bb = (t == 1) ? 128 : 0;
#pragma unroll
            for (int kc = 0; kc < 4; ++kc) {
                short8 afr[2], bfr[2];
#pragma unroll
                for (int mj = 0; mj < 2; ++mj)
                    afr[mj] = *(const short8*)(ldsQ[cur] + (jw * 32 + mj * 16 + l16) * 264 + ab + kc * 32 + quad * 8);
#pragma unroll
                for (int ni = 0; ni < 2; ++ni)
                    bfr[ni] = *(const short8*)(ldsK + (iw * 32 + ni * 16 + l16) * 264 + bb + kc * 32 + quad * 8);
#pragma unroll
                for (int ni = 0; ni < 2; ++ni)
#pragma unroll
                    for (int mj = 0; mj < 2; ++mj)
                        accs[mj][ni] = __builtin_amdgcn_mfma_f32_16x16x32_bf16(afr[mj], bfr[ni], accs[mj][ni], 0, 0, 0);
            }
        }

        // --- epilogue: A = exp(E)*il (dead row -> 1/N); A^T -> ldsA (swizzled)
#pragma unroll
        for (int mj = 0; mj < 2; ++mj) {
#pragma unroll
            for (int ni = 0; ni < 2; ++ni) {
                int irow = iw * 32 + ni * 16 + l16;
                short4_t pk;
#pragma unroll
                for (int r = 0; r < 4; ++r) {
                    int jl = jw * 32 + mj * 16 + quad * 4 + r;
                    float e = accs[mj][ni][r] + bf2f(apv[mj][ni][r]);
                    e = (s_mj[cur][jl] && ion[ni]) ? e : -1.0e9f;
                    float a = s_dead[cur][jl] ? inv_n : __expf(e) * s_il[cur][jl];
                    pk[r] = (short)f2bf(a);
                    if (do_aout)
                        aout[((size_t)(b * N_ + j0 + jl)) * N_ + it * 128 + irow] = a;
                }
                int grp = jw * 4 + mj * 2 + (quad >> 1);       // logical j-group
                int sub = (quad & 1) * 4;
                *(short4_t*)(ldsA + irow * 64 + ((grp ^ (irow & 7)) * 8) + sub) = pk;
            }
        }
        __syncthreads();   // B1: ldsA ready; ldsQ[cur] reads done

        // --- MFMA2: y[32i x 64e per wave] += A^T · V  (k = 64 j)
#pragma unroll
        for (int kcj = 0; kcj < 2; ++kcj) {
            short8 afr2[2];
#pragma unroll
            for (int m2 = 0; m2 < 2; ++m2) {
                int irow = i0y + m2 * 16 + l16;
                int pg = (kcj * 4 + quad) ^ (irow & 7);
                afr2[m2] = *(const short8*)(ldsA + irow * 64 + pg * 8);
            }
#pragma unroll
            for (int ne = 0; ne < 4; ++ne)
#pragma unroll
                for (int m2 = 0; m2 < 2; ++m2)
                    accy[m2][ne] = __builtin_amdgcn_mfma_f32_16x16x32_bf16(afr2[m2], rV[kcj][ne], accy[m2][ne], 0, 0, 0);
        }

        // --- store prefetched next Q + stats
        if (jt < 31) {
#pragma unroll
            for (int i = 0; i < 4; ++i) {
                int c = tid + i * 512;
                int row = c >> 5, grp = c & 31, half = grp >> 4, seg = grp & 15;
                *(short8*)(ldsQ[nxt] + row * 264 + half * 128 + seg * 8) = rQ[i];
            }
            if (tid < 64) {
                s_il[nxt][tid]   = r_il;
                s_dead[nxt][tid] = r_dead;
                s_mj[nxt][tid]   = r_mj;
            }
        }
        __syncthreads();   // B2: buf[nxt] ready; ldsA reads done
    }

    // y store: y[b, i, h*128 + e]
#pragma unroll
    for (int m2 = 0; m2 < 2; ++m2)
#pragma unroll
        for (int ne = 0; ne < 4; ++ne)
#pragma unroll
            for (int r = 0; r < 4; ++r) {
                int irow = i0y + m2 * 16 + quad * 4 + r;
                int e = e0 + ne * 16 + l16;
                yout[((size_t)b * N_ + it * 128 + irow) * D_ + h * DH_ + e] =
                    f2bf(accy[m2][ne][r]);
            }
}

// ---------------------------------------------------------------------------
// Kernel 7: out[m,o] = sum_d y[m,d] Wout[o,d]  (unchanged).
// ---------------------------------------------------------------------------
__global__ __launch_bounds__(256, 4) void outgemm_kernel(
    const u16* __restrict__ A,     // y   [8192][1024] bf16
    const u16* __restrict__ B,     // Wout[1024][1024] bf16 (hi)
    float* __restrict__ C)         // out [8192][1024] fp32
{
    const int nt = blockIdx.x;   // 8
    const int mt = blockIdx.y;   // 64
    const int tid = threadIdx.x, wave = tid >> 6, lane = tid & 63;
    const int quad = lane >> 4, l16 = lane & 15;

    __shared__ __align__(16) u16 sA[128 * 32];
    __shared__ __align__(16) u16 sB[128 * 32];

    const int srow = lane >> 2, scol = (lane & 3) * 8;
    const size_t aoff = ((size_t)(mt * 128) + srow) * 1024 + scol;
    const size_t boff = ((size_t)(nt * 128) + srow) * 1024 + scol;
    const int r0 = wave * 16, r1 = 64 + wave * 16;

    float4_t acc[2][8];
#pragma unroll
    for (int i = 0; i < 2; ++i)
#pragma unroll
        for (int j = 0; j < 8; ++j) acc[i][j] = (float4_t)(0.f);

    for (int kt = 0; kt < 32; ++kt) {
        __syncthreads();
        const int kc0 = kt * 32;
        gl_lds16(A + aoff + (size_t)r0 * 1024 + kc0, &sA[r0 * 32]);
        gl_lds16(A + aoff + (size_t)r1 * 1024 + kc0, &sA[r1 * 32]);
        gl_lds16(B + boff + (size_t)r0 * 1024 + kc0, &sB[r0 * 32]);
        gl_lds16(B + boff + (size_t)r1 * 1024 + kc0, &sB[r1 * 32]);
        __syncthreads();

        short8 afr[2];
#pragma unroll
        for (int mi = 0; mi < 2; ++mi)
            afr[mi] = *(const short8*)(sA + (wave * 32 + mi * 16 + l16) * 32 + quad * 8);
#pragma unroll
        for (int ne = 0; ne < 8; ++ne) {
            short8 bfr = *(const short8*)(sB + (ne * 16 + l16) * 32 + quad * 8);
#pragma unroll
            for (int mi = 0; mi < 2; ++mi)
                acc[mi][ne] = __builtin_amdgcn_mfma_f32_16x16x32_bf16(afr[mi], bfr, acc[mi][ne], 0, 0, 0);
        }
    }

#pragma unroll
    for (int mi = 0; mi < 2; ++mi)
#pragma unroll
        for (int ne = 0; ne < 8; ++ne)
#pragma unroll
            for (int r = 0; r < 4; ++r) {
                int row = mt * 128 + wave * 32 + mi * 16 + quad * 4 + r;
                int col = nt * 128 + ne * 16 + l16;
                C[(size_t)row * D_ + col] = acc[mi][ne][r];
            }
}

// ---------------------------------------------------------------------------
extern "C" void kernel_launch(void* const* d_in, const int* in_sizes, int n_in,
                              void* d_out, int out_size, void* d_ws, size_t ws_size,
                              hipStream_t stream)
{
    const float* x   = (const float*)d_in[0];
    const int*   msk = (const int*)d_in[1];
    const float* Wq  = (const float*)d_in[2];
    const float* Wk  = (const float*)d_in[3];
    const float* Wv  = (const float*)d_in[4];
    const float* Wo  = (const float*)d_in[5];

    float* out  = (float*)d_out;                         // [4,2048,1024] fp32
    float* aout = out + (size_t)BS_ * N_ * D_;           // [4,2048,2048] fp32

    // transient split buffers in d_out (dead before attn/outgemm overwrite)
    u16* Whi  = (u16*)d_out;                       // 2048*1024
    u16* Wlo  = Whi  + (size_t)2048 * 1024;        // 2048*1024
    u16* Wvhi = Wlo  + (size_t)2048 * 1024;        // 1024*1024
    u16* Xhi  = Wvhi + (size_t)1024 * 1024;        // 8192*1024
    u16* Xlo  = Xhi  + (size_t)8192 * 1024;        // 8192*1024

    // workspace (111.4 MB)
    char* w = (char*)d_ws;
    u16* APb = (u16*)w;                       w += (size_t)N_ * N_ * 2;
    const size_t szqk = (size_t)BS_ * H_ * N_ * DH_ * 2;
    u16* Qhi = (u16*)w; w += szqk;
    u16* Qlo = (u16*)w; w += szqk;
    u16* Khi = (u16*)w; w += szqk;
    u16* Klo = (u16*)w; w += szqk;
    u16* VT  = (u16*)w; w += szqk;
    float* lrow = (float*)w;                  w += (size_t)BS_ * H_ * N_ * 4;
    u16* Wohi = (u16*)w;                      w += (size_t)D_ * D_ * 2;
    u16* yb   = (u16*)w;                      w += (size_t)BS_ * N_ * D_ * 2;

    ap_kernel<<<8192, 256, 0, stream>>>((unsigned int*)APb);
    split_kernel<<<12288, 256, 0, stream>>>(x, Wq, Wk, Wv, Wo,
                                            Xhi, Xlo, Whi, Wlo, Wvhi, Wohi);
    qk_gemm<<<dim3(64, 16), 256, 0, stream>>>(Xhi, Xlo, Whi, Wlo,
                                              Qhi, Qlo, Khi, Klo);
    v_gemm<<<dim3(16, 32), 256, 0, stream>>>(Wvhi, Xhi, VT);
    rowstats_kernel<<<dim3(32, 32), 512, 0, stream>>>(Qhi, Qlo, Khi, Klo, APb, msk, lrow);
    attn_kernel<<<dim3(16, 32), 512, 0, stream>>>(Qhi, Qlo, Khi, Klo, VT, APb, msk,
                                                  lrow, yb, aout);
    outgemm_kernel<<<dim3(8, 64), 256, 0, stream>>>(yb, Wohi, out);
}